// Round 1
// baseline (1042.033 us; speedup 1.0000x reference)
//
#include <hip/hip_runtime.h>
#include <hip/hip_bf16.h>

// Problem constants (from reference): n=2,t=16 -> 32 frames; C=64; H=W=64 -> HW=4096;
// M=512 memory slots; 32 groups -> 2 channels/group.
#define NFRAME 32
#define CCH 64
#define HW 4096
#define MSLOT 512
#define TP 64            // pixels per block in main kernel

// workspace layout (float offsets)
#define WS_STATS 0                       // 1024 * 2   (mean, rstd per (frame,group))
#define WS_WT    2048                    // 32*64*64   Wt[b][c][o] = phi_w[o,c]*gamma[c]*rstd*0.125
#define WS_OFF   (2048 + 32*64*64)       // 32*64      off[b][o] (includes phi_b and GN beta/mean, *0.125)
#define WS_MBT   (WS_OFF + 32*64)        // 512*64     mbT[m][c]
#define WS_WZT   (WS_MBT + 512*64)       // 64*64      wzT[c][o]

// ---------------- kernel 1: GroupNorm stats ----------------
// one block per (frame, group): 8192 contiguous floats
__global__ __launch_bounds__(256) void k_stats(const float* __restrict__ x,
                                               float* __restrict__ ws) {
  const int bg = blockIdx.x;                    // 0..1023
  const float4* xp = (const float4*)(x + (size_t)bg * 8192);
  const int t = threadIdx.x;
  float s = 0.f, s2 = 0.f;
#pragma unroll
  for (int i = 0; i < 8; ++i) {
    float4 v = xp[t + i * 256];
    s  += v.x + v.y + v.z + v.w;
    s2 += v.x * v.x + v.y * v.y + v.z * v.z + v.w * v.w;
  }
  for (int off = 32; off; off >>= 1) {
    s  += __shfl_down(s,  off, 64);
    s2 += __shfl_down(s2, off, 64);
  }
  __shared__ float ls[8];
  const int wid = t >> 6;
  if ((t & 63) == 0) { ls[wid * 2] = s; ls[wid * 2 + 1] = s2; }
  __syncthreads();
  if (t == 0) {
    float S = 0.f, S2 = 0.f;
#pragma unroll
    for (int w = 0; w < 4; ++w) { S += ls[w * 2]; S2 += ls[w * 2 + 1]; }
    float mean = S * (1.f / 8192.f);
    float var  = S2 * (1.f / 8192.f) - mean * mean;
    float rstd = rsqrtf(var + 1e-6f);
    ws[WS_STATS + bg * 2]     = mean;
    ws[WS_STATS + bg * 2 + 1] = rstd;
  }
}

// ---------------- kernel 2: fold GN + scale into conv weights ----------------
__global__ __launch_bounds__(64) void k_prep(const float* __restrict__ phi_w,
                                             const float* __restrict__ phi_b,
                                             const float* __restrict__ gamma,
                                             const float* __restrict__ beta,
                                             float* __restrict__ ws) {
  const int b = blockIdx.x;     // frame
  const int o = threadIdx.x;    // out channel
  float offacc = 0.f;
  for (int c = 0; c < CCH; ++c) {
    const int g = c >> 1;
    const float mean = ws[WS_STATS + (b * 32 + g) * 2];
    const float rstd = ws[WS_STATS + (b * 32 + g) * 2 + 1];
    const float a = gamma[c] * rstd;
    const float d = beta[c] - mean * a;
    const float w = phi_w[o * 64 + c];
    ws[WS_WT + b * 4096 + c * 64 + o] = w * a * 0.125f;   // 1/sqrt(64) folded in
    offacc += w * d;
  }
  ws[WS_OFF + b * 64 + o] = (offacc + phi_b[o]) * 0.125f;
}

// ---------------- kernel 3: transposes of mb and wz_w ----------------
__global__ __launch_bounds__(256) void k_tr(const float* __restrict__ mb,
                                            const float* __restrict__ wz_w,
                                            float* __restrict__ ws) {
  const int i = blockIdx.x * 256 + threadIdx.x;
  if (i < MSLOT * CCH) {
    const int m = i >> 6, c = i & 63;
    ws[WS_MBT + i] = mb[c * MSLOT + m];          // mbT[m][c]
  } else {
    const int j = i - MSLOT * CCH;
    if (j < CCH * CCH) {
      const int c = j >> 6, o = j & 63;
      ws[WS_WZT + j] = wz_w[o * 64 + c];         // wzT[c][o]
    }
  }
}

// ---------------- kernel 4: fused phi -> attention -> wz -> residual ----------------
// grid: 32 frames * 64 tiles; block 256 = 4 waves.
// lane (p) = pixel within 64-pixel tile; wave (q) = role quarter.
__global__ __launch_bounds__(256, 3) void k_main(const float* __restrict__ x,
                                                 const float* __restrict__ ws,
                                                 const float* __restrict__ mb,
                                                 const float* __restrict__ wz_b,
                                                 float* __restrict__ out) {
  const int b  = blockIdx.x >> 6;
  const int p0 = (blockIdx.x & 63) * TP;
  const int tid = threadIdx.x;
  const int p = tid & 63;   // lane -> pixel
  const int q = tid >> 6;   // wave -> quarter role

  __shared__ __hip_bfloat16 af[256 * 64];   // 32KB: raw logits [m_rel][p] for current half
  __shared__ __hip_bfloat16 ph[64 * 64];    // 8KB:  phi [o][p]; reused later as y [c][p]
  __shared__ float red[4 * 64 * 2];         // per-(wave,pixel) partial max / sumexp

  // ---- phase 0: phi = Wt^T x + off (GN + 1x1 conv + 1/8 scale folded) ----
  const float* Wt   = ws + WS_WT + b * 4096;
  const float* offp = ws + WS_OFF + b * 64;
  const float* xb   = x + (size_t)b * CCH * HW + p0 + p;
  float phi[16];
#pragma unroll
  for (int i = 0; i < 16; ++i) phi[i] = offp[q * 16 + i];
  for (int c = 0; c < CCH; ++c) {
    const float xv = xb[(size_t)c * HW];
    const float4* wr = (const float4*)(Wt + c * 64 + q * 16);
#pragma unroll
    for (int j = 0; j < 4; ++j) {
      float4 w4 = wr[j];
      phi[j * 4 + 0] += w4.x * xv;
      phi[j * 4 + 1] += w4.y * xv;
      phi[j * 4 + 2] += w4.z * xv;
      phi[j * 4 + 3] += w4.w * xv;
    }
  }
#pragma unroll
  for (int i = 0; i < 16; ++i) ph[(q * 16 + i) * 64 + p] = __float2bfloat16(phi[i]);
  __syncthreads();

  // ---- flash-style softmax-attention over M in two halves of 256 ----
  float Mr = -1e30f, Lr = 0.f;
  float y[16];
#pragma unroll
  for (int i = 0; i < 16; ++i) y[i] = 0.f;

  for (int half = 0; half < 2; ++half) {
    // f-pass: this wave covers m in [half*256 + q*64, +64), two chunks of 32
    float hm = -1e30f, hl = 0.f;
#pragma unroll
    for (int ch = 0; ch < 2; ++ch) {
      const int mbase = half * 256 + q * 64 + ch * 32;
      float f[32];
#pragma unroll
      for (int i = 0; i < 32; ++i) f[i] = 0.f;
      for (int c = 0; c < CCH; ++c) {
        const float pv = __bfloat162float(ph[c * 64 + p]);
        const float4* mr = (const float4*)(mb + c * MSLOT + mbase);
#pragma unroll
        for (int j = 0; j < 8; ++j) {
          float4 m4 = mr[j];
          f[j * 4 + 0] += pv * m4.x;
          f[j * 4 + 1] += pv * m4.y;
          f[j * 4 + 2] += pv * m4.z;
          f[j * 4 + 3] += pv * m4.w;
        }
      }
      float cm = f[0];
#pragma unroll
      for (int i = 1; i < 32; ++i) cm = fmaxf(cm, f[i]);
      const float nm = fmaxf(hm, cm);
      hl *= __expf(hm - nm);
#pragma unroll
      for (int i = 0; i < 32; ++i) hl += __expf(f[i] - nm);
      hm = nm;
#pragma unroll
      for (int i = 0; i < 32; ++i)
        af[(q * 64 + ch * 32 + i) * 64 + p] = __float2bfloat16(f[i]);
    }
    red[(q * 64 + p) * 2]     = hm;
    red[(q * 64 + p) * 2 + 1] = hl;
    __syncthreads();

    // merge running max/sum across the 4 waves (every thread redundantly, deterministic)
    float gm = Mr;
#pragma unroll
    for (int w = 0; w < 4; ++w) gm = fmaxf(gm, red[(w * 64 + p) * 2]);
    const float fac = __expf(Mr - gm);
    Lr *= fac;
#pragma unroll
    for (int i = 0; i < 16; ++i) y[i] *= fac;
#pragma unroll
    for (int w = 0; w < 4; ++w)
      Lr += red[(w * 64 + p) * 2 + 1] * __expf(red[(w * 64 + p) * 2] - gm);
    Mr = gm;

    // y-pass: this wave accumulates channels [q*16, +16) over the half's 256 slots
    const float* mbT = ws + WS_MBT + half * 256 * 64 + q * 16;
    for (int mrel = 0; mrel < 256; ++mrel) {
      const float a = __expf(__bfloat162float(af[mrel * 64 + p]) - Mr);
      const float4* vr = (const float4*)(mbT + mrel * 64);
#pragma unroll
      for (int j = 0; j < 4; ++j) {
        float4 v4 = vr[j];
        y[j * 4 + 0] += a * v4.x;
        y[j * 4 + 1] += a * v4.y;
        y[j * 4 + 2] += a * v4.z;
        y[j * 4 + 3] += a * v4.w;
      }
    }
    __syncthreads();   // before af/red reuse in next half
  }

  // ---- normalize, stash y (reuse ph), project with wz, add residual ----
  const float invL = 1.f / Lr;
#pragma unroll
  for (int i = 0; i < 16; ++i)
    ph[(q * 16 + i) * 64 + p] = __float2bfloat16(y[i] * invL);
  __syncthreads();

  float acc[16];
#pragma unroll
  for (int i = 0; i < 16; ++i) acc[i] = wz_b[q * 16 + i];
  const float* wzT = ws + WS_WZT + q * 16;
  for (int c = 0; c < CCH; ++c) {
    const float yv = __bfloat162float(ph[c * 64 + p]);
    const float4* wr = (const float4*)(wzT + c * 64);
#pragma unroll
    for (int j = 0; j < 4; ++j) {
      float4 w4 = wr[j];
      acc[j * 4 + 0] += yv * w4.x;
      acc[j * 4 + 1] += yv * w4.y;
      acc[j * 4 + 2] += yv * w4.z;
      acc[j * 4 + 3] += yv * w4.w;
    }
  }
  float* ob = out + (size_t)b * CCH * HW + p0 + p;
  const float* xr = x + (size_t)b * CCH * HW + p0 + p;
#pragma unroll
  for (int i = 0; i < 16; ++i)
    ob[(size_t)(q * 16 + i) * HW] = acc[i] + xr[(size_t)(q * 16 + i) * HW];
}

extern "C" void kernel_launch(void* const* d_in, const int* in_sizes, int n_in,
                              void* d_out, int out_size, void* d_ws, size_t ws_size,
                              hipStream_t stream) {
  const float* x     = (const float*)d_in[0];
  const float* gamma = (const float*)d_in[1];
  const float* beta  = (const float*)d_in[2];
  const float* phi_w = (const float*)d_in[3];
  const float* phi_b = (const float*)d_in[4];
  const float* mb    = (const float*)d_in[5];
  const float* wz_w  = (const float*)d_in[6];
  const float* wz_b  = (const float*)d_in[7];
  float* out = (float*)d_out;
  float* ws  = (float*)d_ws;

  k_stats<<<1024, 256, 0, stream>>>(x, ws);
  k_prep<<<32, 64, 0, stream>>>(phi_w, phi_b, gamma, beta, ws);
  k_tr<<<144, 256, 0, stream>>>(mb, wz_w, ws);
  k_main<<<NFRAME * (HW / TP), 256, 0, stream>>>(x, ws, mb, wz_b, out);
}

// Round 2
// 144.320 us; speedup vs baseline: 7.2203x; 7.2203x over previous
//
#include <hip/hip_runtime.h>
#include <hip/hip_bf16.h>

// n=2,t=16 -> 32 frames; C=64; HW=4096; M=512; 32 groups (2 ch/group).
#define NFRAME 32
#define CCH 64
#define HW 4096
#define MSLOT 512

typedef __attribute__((ext_vector_type(8))) short s16x8;   // 8 bf16 (4 VGPR) MFMA A/B frag
typedef __attribute__((ext_vector_type(4))) float f32x4;   // MFMA C/D frag
typedef unsigned short u16;
typedef unsigned int u32;

// workspace layout: f32 region then bf16 (u16) region
#define WS_STATS 0          // 1024*2 f32 (mean,rstd per frame,group)
#define WS_OFF   2048       // 32*64 f32
#define WS_BF16  4096       // u16 region starts at this float offset
#define BW_WF   0                   // Wfold bf16 [32][64 o][64 c]
#define BW_MBT  131072              // mbT  bf16 [512 m][64 c]
#define BW_MBB  (131072 + 32768)    // mbB  bf16 [64 c][512 m]
#define BW_WZ   (131072 + 65536)    // wz   bf16 [64 o][64 c]

static __device__ __forceinline__ u16 f2b(float f) {
  __hip_bfloat16 h = __float2bfloat16(f);
  return *reinterpret_cast<u16*>(&h);
}

// ---------------- kernel 1: GroupNorm stats (one block per frame,group) ----------------
__global__ __launch_bounds__(256) void k_stats(const float* __restrict__ x,
                                               float* __restrict__ ws) {
  const int bg = blockIdx.x;                    // 0..1023
  const float4* xp = (const float4*)(x + (size_t)bg * 8192);
  const int t = threadIdx.x;
  float s = 0.f, s2 = 0.f;
#pragma unroll
  for (int i = 0; i < 8; ++i) {
    float4 v = xp[t + i * 256];
    s  += v.x + v.y + v.z + v.w;
    s2 += v.x * v.x + v.y * v.y + v.z * v.z + v.w * v.w;
  }
  for (int off = 32; off; off >>= 1) {
    s  += __shfl_down(s,  off, 64);
    s2 += __shfl_down(s2, off, 64);
  }
  __shared__ float ls[8];
  const int wid = t >> 6;
  if ((t & 63) == 0) { ls[wid * 2] = s; ls[wid * 2 + 1] = s2; }
  __syncthreads();
  if (t == 0) {
    float S = 0.f, S2 = 0.f;
#pragma unroll
    for (int w = 0; w < 4; ++w) { S += ls[w * 2]; S2 += ls[w * 2 + 1]; }
    float mean = S * (1.f / 8192.f);
    float var  = S2 * (1.f / 8192.f) - mean * mean;
    float rstd = rsqrtf(var + 1e-6f);
    ws[WS_STATS + bg * 2]     = mean;
    ws[WS_STATS + bg * 2 + 1] = rstd;
  }
}

// ---------------- kernel 2: fold GN + 1/8 scale into bf16 conv weights ----------------
__global__ __launch_bounds__(64) void k_prep(const float* __restrict__ phi_w,
                                             const float* __restrict__ phi_b,
                                             const float* __restrict__ gamma,
                                             const float* __restrict__ beta,
                                             float* __restrict__ ws) {
  const int b = blockIdx.x;     // frame
  const int o = threadIdx.x;    // out channel
  u16* wf = (u16*)(ws + WS_BF16) + BW_WF + ((size_t)b * 64 + o) * 64;
  float offacc = 0.f;
  for (int c = 0; c < CCH; ++c) {
    const int g = c >> 1;
    const float mean = ws[WS_STATS + (b * 32 + g) * 2];
    const float rstd = ws[WS_STATS + (b * 32 + g) * 2 + 1];
    const float a = gamma[c] * rstd;
    const float d = beta[c] - mean * a;
    const float w = phi_w[o * 64 + c];
    wf[c] = f2b(w * a * 0.125f);
    offacc += w * d;
  }
  ws[WS_OFF + b * 64 + o] = (offacc + phi_b[o]) * 0.125f;
}

// ---------------- kernel 3: bf16 casts/transposes of mb and wz_w ----------------
__global__ __launch_bounds__(256) void k_tr(const float* __restrict__ mb,
                                            const float* __restrict__ wz_w,
                                            float* __restrict__ ws) {
  u16* wbw = (u16*)(ws + WS_BF16);
  const int i = blockIdx.x * 256 + threadIdx.x;
  if (i < 32768) {                       // mbT[m][c] = mb[c][m]
    const int m = i >> 6, c = i & 63;
    wbw[BW_MBT + i] = f2b(mb[c * MSLOT + m]);
  } else if (i < 65536) {                // mbB[c][m] = mb[c][m]
    const int j = i - 32768;
    wbw[BW_MBB + j] = f2b(mb[j]);
  } else if (i < 69632) {                // wz[o][c]
    const int j = i - 65536;
    wbw[BW_WZ + j] = f2b(wz_w[j]);
  }
}

// ---------------- kernel 4: MFMA phi -> flash attention -> MFMA wz + residual ----------------
// grid: 32 frames * 64 pixel-tiles; 4 waves; wave owns 16 pixels for attention.
__global__ __launch_bounds__(256, 3) void k_main(const float* __restrict__ x,
                                                 const float* __restrict__ ws,
                                                 const float* __restrict__ wz_b,
                                                 float* __restrict__ out) {
  const int b  = blockIdx.x >> 6;
  const int p0 = (blockIdx.x & 63) * 64;
  const int tid  = threadIdx.x;
  const int w    = tid >> 6;        // wave id
  const int lane = tid & 63;
  const int g  = lane >> 4;
  const int l4 = lane & 15;

  const u16* wb = (const u16*)(ws + WS_BF16);

  __shared__ u16 xt[64 * 64];       // xT[p][c ^ ((p&7)<<3)] bf16; reused as yT
  __shared__ u16 pht[64 * 64];      // phiT[p][o ^ ((p&7)<<3)] bf16
  __shared__ u16 pbuf[4][16 * 40];  // per-wave P chunk [16 p][32 m + pad]

  // ---- stage x tile, transposed + swizzled, bf16 ----
  {
    const int p = lane;
    const int sw = (p & 7) << 3;
    const float* xc = x + (size_t)b * CCH * HW + p0 + p;
#pragma unroll
    for (int j = 0; j < 8; ++j) {
      const int c = w * 16 + j * 2;
      const float v0 = xc[(size_t)c * HW];
      const float v1 = xc[(size_t)(c + 1) * HW];
      const u32 pk = (u32)f2b(v0) | ((u32)f2b(v1) << 16);
      *(u32*)&xt[p * 64 + (c ^ sw)] = pk;
    }
  }
  __syncthreads();

  // ---- phase A: phi = Wfold @ x + off  -> phiT LDS ----
  {
    const int o0 = w * 16;
    const u16* wfp = wb + BW_WF + ((size_t)b * 64 + o0 + l4) * 64 + g * 8;
    const s16x8 a0 = *(const s16x8*)(wfp);
    const s16x8 a1 = *(const s16x8*)(wfp + 32);
    float offv[4];
#pragma unroll
    for (int r = 0; r < 4; ++r) offv[r] = ws[WS_OFF + b * 64 + o0 + g * 4 + r];
#pragma unroll
    for (int pt = 0; pt < 4; ++pt) {
      const int prow = pt * 16 + l4;
      const int sw = (l4 & 7) << 3;
      const s16x8 b0 = *(const s16x8*)&xt[prow * 64 + ((g * 8) ^ sw)];
      const s16x8 b1 = *(const s16x8*)&xt[prow * 64 + ((32 + g * 8) ^ sw)];
      f32x4 acc = {0.f, 0.f, 0.f, 0.f};
      acc = __builtin_amdgcn_mfma_f32_16x16x32_bf16(a0, b0, acc, 0, 0, 0);
      acc = __builtin_amdgcn_mfma_f32_16x16x32_bf16(a1, b1, acc, 0, 0, 0);
#pragma unroll
      for (int r = 0; r < 4; ++r) {
        const int o = o0 + g * 4 + r;                // D row
        pht[prow * 64 + (o ^ sw)] = f2b(acc[r] + offv[r]);
      }
    }
  }
  __syncthreads();

  // ---- attention: wave w owns pixels [w*16, w*16+16) ----
  const int pr = w * 16 + l4;
  const int swp = (l4 & 7) << 3;
  const s16x8 qa0 = *(const s16x8*)&pht[pr * 64 + ((g * 8) ^ swp)];
  const s16x8 qa1 = *(const s16x8*)&pht[pr * 64 + ((32 + g * 8) ^ swp)];

  f32x4 Y[4];
#pragma unroll
  for (int nt = 0; nt < 4; ++nt) Y[nt] = (f32x4){0.f, 0.f, 0.f, 0.f};
  float Mr[4], Lr[4];
#pragma unroll
  for (int r = 0; r < 4; ++r) { Mr[r] = -1e30f; Lr[r] = 0.f; }

  u16* pw = &pbuf[w][0];

  for (int h = 0; h < 2; ++h) {
    const int m0 = h * 256;
    // QK^T: S[16p x 256m] for this half
    f32x4 s[16];
#pragma unroll
    for (int t = 0; t < 16; ++t) {
      const u16* kp = wb + BW_MBT + (size_t)(m0 + t * 16 + l4) * 64 + g * 8;
      const s16x8 k0 = *(const s16x8*)(kp);
      const s16x8 k1 = *(const s16x8*)(kp + 32);
      f32x4 acc = {0.f, 0.f, 0.f, 0.f};
      acc = __builtin_amdgcn_mfma_f32_16x16x32_bf16(qa0, k0, acc, 0, 0, 0);
      acc = __builtin_amdgcn_mfma_f32_16x16x32_bf16(qa1, k1, acc, 0, 0, 0);
      s[t] = acc;
    }
    // row max (per r: in-lane over tiles, then 16-lane butterfly)
    float mx[4];
#pragma unroll
    for (int r = 0; r < 4; ++r) {
      float m = s[0][r];
#pragma unroll
      for (int t = 1; t < 16; ++t) m = fmaxf(m, s[t][r]);
      m = fmaxf(m, __shfl_xor(m, 1, 64));
      m = fmaxf(m, __shfl_xor(m, 2, 64));
      m = fmaxf(m, __shfl_xor(m, 4, 64));
      m = fmaxf(m, __shfl_xor(m, 8, 64));
      mx[r] = m;
    }
    // online merge
    f32x4 facv;
#pragma unroll
    for (int r = 0; r < 4; ++r) {
      const float nM = fmaxf(Mr[r], mx[r]);
      const float fac = __expf(Mr[r] - nM);
      Lr[r] *= fac;
      Mr[r] = nM;
      facv[r] = fac;
    }
#pragma unroll
    for (int nt = 0; nt < 4; ++nt) Y[nt] *= facv;

    float lp[4] = {0.f, 0.f, 0.f, 0.f};
#pragma unroll
    for (int k = 0; k < 8; ++k) {
      // prefetch V b-frags (L2-hot) before the LDS round-trip
      s16x8 vf[4];
#pragma unroll
      for (int nt = 0; nt < 4; ++nt) {
        const u16* vp = wb + BW_MBB + (size_t)(nt * 16 + l4) * MSLOT + m0 + k * 32 + g * 8;
        vf[nt] = *(const s16x8*)(vp);
      }
      // exp + P-chunk transpose into padded LDS
#pragma unroll
      for (int t2 = 0; t2 < 2; ++t2) {
        const int t = k * 2 + t2;
#pragma unroll
        for (int r = 0; r < 4; ++r) {
          const float e = __expf(s[t][r] - Mr[r]);
          lp[r] += e;
          pw[(g * 4 + r) * 40 + t2 * 16 + l4] = f2b(e);
        }
      }
      asm volatile("s_waitcnt lgkmcnt(0)" ::: "memory");
      __builtin_amdgcn_sched_barrier(0);
      const s16x8 pa = *(const s16x8*)&pw[l4 * 40 + g * 8];
#pragma unroll
      for (int nt = 0; nt < 4; ++nt)
        Y[nt] = __builtin_amdgcn_mfma_f32_16x16x32_bf16(pa, vf[nt], Y[nt], 0, 0, 0);
    }
#pragma unroll
    for (int r = 0; r < 4; ++r) {
      float l = lp[r];
      l += __shfl_xor(l, 1, 64);
      l += __shfl_xor(l, 2, 64);
      l += __shfl_xor(l, 4, 64);
      l += __shfl_xor(l, 8, 64);
      Lr[r] += l;
    }
  }

  // normalize and write yT (reuse xt buffer)
  {
    f32x4 invv;
#pragma unroll
    for (int r = 0; r < 4; ++r) invv[r] = 1.f / Lr[r];
#pragma unroll
    for (int nt = 0; nt < 4; ++nt) Y[nt] *= invv;
#pragma unroll
    for (int nt = 0; nt < 4; ++nt)
#pragma unroll
      for (int r = 0; r < 4; ++r) {
        const int p = w * 16 + g * 4 + r;
        const int c = nt * 16 + l4;
        xt[p * 64 + (c ^ ((p & 7) << 3))] = f2b(Y[nt][r]);
      }
  }
  __syncthreads();

  // ---- phase D: out = wz @ y + wz_b + x ----
  {
    const int o0 = w * 16;
    const u16* wzp = wb + BW_WZ + (size_t)(o0 + l4) * 64 + g * 8;
    const s16x8 a0 = *(const s16x8*)(wzp);
    const s16x8 a1 = *(const s16x8*)(wzp + 32);
    float bz[4];
#pragma unroll
    for (int r = 0; r < 4; ++r) bz[r] = wz_b[o0 + g * 4 + r];
#pragma unroll
    for (int pt = 0; pt < 4; ++pt) {
      const int prow = pt * 16 + l4;
      const int sw = (l4 & 7) << 3;
      const s16x8 b0 = *(const s16x8*)&xt[prow * 64 + ((g * 8) ^ sw)];
      const s16x8 b1 = *(const s16x8*)&xt[prow * 64 + ((32 + g * 8) ^ sw)];
      f32x4 acc = {0.f, 0.f, 0.f, 0.f};
      acc = __builtin_amdgcn_mfma_f32_16x16x32_bf16(a0, b0, acc, 0, 0, 0);
      acc = __builtin_amdgcn_mfma_f32_16x16x32_bf16(a1, b1, acc, 0, 0, 0);
#pragma unroll
      for (int r = 0; r < 4; ++r) {
        const size_t idx = ((size_t)b * 64 + o0 + g * 4 + r) * HW + p0 + pt * 16 + l4;
        out[idx] = acc[r] + bz[r] + x[idx];
      }
    }
  }
}

extern "C" void kernel_launch(void* const* d_in, const int* in_sizes, int n_in,
                              void* d_out, int out_size, void* d_ws, size_t ws_size,
                              hipStream_t stream) {
  const float* x     = (const float*)d_in[0];
  const float* gamma = (const float*)d_in[1];
  const float* beta  = (const float*)d_in[2];
  const float* phi_w = (const float*)d_in[3];
  const float* phi_b = (const float*)d_in[4];
  const float* mb    = (const float*)d_in[5];
  const float* wz_w  = (const float*)d_in[6];
  const float* wz_b  = (const float*)d_in[7];
  float* out = (float*)d_out;
  float* ws  = (float*)d_ws;

  k_stats<<<1024, 256, 0, stream>>>(x, ws);
  k_prep<<<32, 64, 0, stream>>>(phi_w, phi_b, gamma, beta, ws);
  k_tr<<<272, 256, 0, stream>>>(mb, wz_w, ws);
  k_main<<<NFRAME * 64, 256, 0, stream>>>(x, ws, wz_b, out);
}

// Round 3
// 71.068 us; speedup vs baseline: 14.6624x; 2.0307x over previous
//
#include <hip/hip_runtime.h>
#include <hip/hip_bf16.h>

// n=2,t=16 -> 32 frames; C=64; HW=4096; M=512; 32 groups (2 ch/group).
#define NFRAME 32
#define CCH 64
#define HW 4096
#define MSLOT 512

typedef __attribute__((ext_vector_type(8))) short s16x8;   // 8 bf16 MFMA A/B frag
typedef __attribute__((ext_vector_type(4))) float f32x4;   // MFMA C/D frag
typedef __attribute__((ext_vector_type(4))) unsigned short us4;
typedef unsigned short u16;
typedef unsigned int u32;

// f32 workspace offsets
#define WS_STATS 0          // 1024*2 f32
#define WS_OFF   2048       // 32*64 f32
#define WS_BF16  4096       // u16 region starts here (float offset)
// u16 offsets inside bf16 region
#define BW_WFRAW 0                         // [32][64 o][64 c] folded phi weights (raw)
#define BW_KF    131072                    // [32 mt][2 f][64 lane][8]  QK^T A-frags (K rows m)
#define BW_VF    163840                    // [16 q][4 ct][64 lane][8]  PV A-frags (V^T rows c)
#define BW_WZF   196608                    // [4 ot][2 f][64 lane][8]   wz A-frags
#define BW_WFF   200704                    // [32 b][4 ot][2 f][64 lane][8] phi A-frags

// exp2-domain scale: 1/sqrt(64) * log2(e)
#define QSCALE 0.18033688011112042f

static __device__ __forceinline__ u16 f2b(float f) {
  __hip_bfloat16 h = __float2bfloat16(f);
  return *reinterpret_cast<u16*>(&h);
}
static __device__ __forceinline__ float b2f(u16 v) {
  __hip_bfloat16 h = *reinterpret_cast<__hip_bfloat16*>(&v);
  return __bfloat162float(h);
}

// ---------------- kernel 1: GroupNorm stats ----------------
__global__ __launch_bounds__(256) void k_stats(const float* __restrict__ x,
                                               float* __restrict__ ws) {
  const int bg = blockIdx.x;
  const float4* xp = (const float4*)(x + (size_t)bg * 8192);
  const int t = threadIdx.x;
  float s = 0.f, s2 = 0.f;
#pragma unroll
  for (int i = 0; i < 8; ++i) {
    float4 v = xp[t + i * 256];
    s  += v.x + v.y + v.z + v.w;
    s2 += v.x * v.x + v.y * v.y + v.z * v.z + v.w * v.w;
  }
  for (int off = 32; off; off >>= 1) {
    s  += __shfl_down(s,  off, 64);
    s2 += __shfl_down(s2, off, 64);
  }
  __shared__ float ls[8];
  const int wid = t >> 6;
  if ((t & 63) == 0) { ls[wid * 2] = s; ls[wid * 2 + 1] = s2; }
  __syncthreads();
  if (t == 0) {
    float S = 0.f, S2 = 0.f;
#pragma unroll
    for (int w = 0; w < 4; ++w) { S += ls[w * 2]; S2 += ls[w * 2 + 1]; }
    float mean = S * (1.f / 8192.f);
    float var  = S2 * (1.f / 8192.f) - mean * mean;
    float rstd = rsqrtf(var + 1e-6f);
    ws[WS_STATS + bg * 2]     = mean;
    ws[WS_STATS + bg * 2 + 1] = rstd;
  }
}

// ---------------- kernel 2: fold GN + scale into bf16 phi weights ----------------
__global__ __launch_bounds__(64) void k_prep(const float* __restrict__ phi_w,
                                             const float* __restrict__ phi_b,
                                             const float* __restrict__ gamma,
                                             const float* __restrict__ beta,
                                             float* __restrict__ ws) {
  const int b = blockIdx.x;
  const int o = threadIdx.x;
  u16* wf = (u16*)(ws + WS_BF16) + BW_WFRAW + ((size_t)b * 64 + o) * 64;
  float offacc = 0.f;
  for (int c = 0; c < CCH; ++c) {
    const int g = c >> 1;
    const float mean = ws[WS_STATS + (b * 32 + g) * 2];
    const float rstd = ws[WS_STATS + (b * 32 + g) * 2 + 1];
    const float a = gamma[c] * rstd;
    const float d = beta[c] - mean * a;
    const float wv = phi_w[o * 64 + c];
    wf[c] = f2b(wv * a * QSCALE);
    offacc += wv * d;
  }
  ws[WS_OFF + b * 64 + o] = (offacc + phi_b[o]) * QSCALE;
}

// ---------------- kernel 3: build fragment-ordered operand tables ----------------
// runs after k_prep (stream order). 200704 threads, one u16 each.
__global__ __launch_bounds__(256) void k_tr(const float* __restrict__ mb,
                                            const float* __restrict__ wz_w,
                                            float* __restrict__ ws) {
  u16* wbw = (u16*)(ws + WS_BF16);
  const int i = blockIdx.x * 256 + threadIdx.x;
  if (i < 32768) {                           // KF[mt][f][lane][j]
    const int mt = i >> 10, f = (i >> 9) & 1, l = (i >> 3) & 63, j = i & 7;
    const int c = f * 32 + ((l >> 4) & 3) * 8 + j;
    const int m = mt * 16 + (l & 15);
    wbw[BW_KF + i] = f2b(mb[c * MSLOT + m]);
  } else if (i < 65536) {                    // VF[q][ct][lane][j]
    const int i2 = i - 32768;
    const int q = i2 >> 11, ct = (i2 >> 9) & 3, l = (i2 >> 3) & 63, j = i2 & 7;
    const int c = ct * 16 + (l & 15);
    const int m = q * 32 + ((l >> 4) & 3) * 8 + j;
    wbw[BW_VF + i2] = f2b(mb[c * MSLOT + m]);
  } else if (i < 69632) {                    // WZF[ot][f][lane][j]
    const int i3 = i - 65536;
    const int ot = i3 >> 10, f = (i3 >> 9) & 1, l = (i3 >> 3) & 63, j = i3 & 7;
    const int o = ot * 16 + (l & 15);
    const int c = f * 32 + ((l >> 4) & 3) * 8 + j;
    wbw[BW_WZF + i3] = f2b(wz_w[o * 64 + c]);
  } else {                                   // WFF[b][ot][f][lane][j] (u16 copy of WFRAW)
    const int i4 = i - 69632;                // < 131072
    const int b = i4 >> 12, ot = (i4 >> 10) & 3, f = (i4 >> 9) & 1,
              l = (i4 >> 3) & 63, j = i4 & 7;
    const int o = ot * 16 + (l & 15);
    const int c = f * 32 + ((l >> 4) & 3) * 8 + j;
    wbw[BW_WFF + i4] = wbw[BW_WFRAW + ((size_t)b * 64 + o) * 64 + c];
  }
}

// ---------------- kernel 4: fused phi -> m-split flash attention -> merge -> wz ----------------
// grid: 32 frames * 64 pixel-tiles; 4 waves; wave w owns m-quarter [w*128, +128) for ALL 64 pixels.
// Empirical D-layout (validated r2): mfma(A,B) -> D[row = A-row = (lane>>4)*4+reg][col = B-row = lane&15].
__global__ __launch_bounds__(256, 2) void k_main(const float* __restrict__ x,
                                                 const float* __restrict__ ws,
                                                 const float* __restrict__ wz_b,
                                                 float* __restrict__ out) {
  const int b  = blockIdx.x >> 6;
  const int p0 = (blockIdx.x & 63) * 64;
  const int tid  = threadIdx.x;
  const int w    = tid >> 6;
  const int lane = tid & 63;
  const int g  = lane >> 4;
  const int l4 = lane & 15;

  const u16* wb = (const u16*)(ws + WS_BF16);

  // LDS: [stats 2K][yT 8K][xt 8K][pht 8K][pbuf 16K] ; yp (34K) overlays xt..pbuf after m-loop
  __shared__ __align__(16) unsigned char lds[45056];
  float* smax = (float*)lds;                    // [4w][4pt][16 l4]
  float* ssum = (float*)(lds + 1024);
  u16* yT   = (u16*)(lds + 2048);               // [64 p][64 c] swizzled
  u16* xt   = (u16*)(lds + 10240);              // [64 p][64 c] swizzled
  u16* pht  = (u16*)(lds + 18432);              // [64 p][64 o] swizzled
  u16* pbuf = (u16*)(lds + 26624);              // [4w][4pt][16 p][32 m] xor-swz
  u16* yp   = (u16*)(lds + 10240);              // overlay [4w][64 p][68]

  // ---- stage x tile (bf16, transposed, swizzled) ----
  {
    const int p = lane;
    const int sw = (p & 7) << 3;
    const float* xc = x + (size_t)b * CCH * HW + p0 + p;
#pragma unroll
    for (int j = 0; j < 8; ++j) {
      const int c = w * 16 + j * 2;
      const float v0 = xc[(size_t)c * HW];
      const float v1 = xc[(size_t)(c + 1) * HW];
      const u32 pk = (u32)f2b(v0) | ((u32)f2b(v1) << 16);
      *(u32*)&xt[p * 64 + (c ^ sw)] = pk;
    }
  }
  __syncthreads();

  // ---- phase A: phi = Wfold @ x + off ; wave computes o-block w*16.. for all 64 p ----
  {
    const s16x8 a0 = *(const s16x8*)(wb + BW_WFF + ((((size_t)b * 4 + w) * 2 + 0) * 64 + lane) * 8);
    const s16x8 a1 = *(const s16x8*)(wb + BW_WFF + ((((size_t)b * 4 + w) * 2 + 1) * 64 + lane) * 8);
    float offv[4];
#pragma unroll
    for (int r = 0; r < 4; ++r) offv[r] = ws[WS_OFF + b * 64 + w * 16 + g * 4 + r];
#pragma unroll
    for (int pt = 0; pt < 4; ++pt) {
      const int p = pt * 16 + l4;
      const int sw = (l4 & 7) << 3;
      const s16x8 b0 = *(const s16x8*)&xt[p * 64 + ((g * 8) ^ sw)];
      const s16x8 b1 = *(const s16x8*)&xt[p * 64 + ((32 + g * 8) ^ sw)];
      f32x4 acc = {0.f, 0.f, 0.f, 0.f};
      acc = __builtin_amdgcn_mfma_f32_16x16x32_bf16(a0, b0, acc, 0, 0, 0);
      acc = __builtin_amdgcn_mfma_f32_16x16x32_bf16(a1, b1, acc, 0, 0, 0);
      us4 pk;
#pragma unroll
      for (int r = 0; r < 4; ++r) pk[r] = f2b(acc[r] + offv[r]);
      *(us4*)&pht[p * 64 + ((w * 16 + g * 4) ^ sw)] = pk;   // phi[p][o]
    }
  }
  __syncthreads();

  // ---- load Q-frags (loop-invariant) ----
  s16x8 q[4][2];
#pragma unroll
  for (int pt = 0; pt < 4; ++pt) {
    const int p = pt * 16 + l4;
    const int sw = (l4 & 7) << 3;
    q[pt][0] = *(const s16x8*)&pht[p * 64 + ((g * 8) ^ sw)];
    q[pt][1] = *(const s16x8*)&pht[p * 64 + ((32 + g * 8) ^ sw)];
  }
  __syncthreads();   // pht must be fully read before any wave overwrites (yp overlay)

  // ---- m-split flash attention: 4 sub-chunks of 32 m ----
  f32x4 Y[4][4];     // [pt][ct]: c = ct*16+g*4+r, p = pt*16+l4
#pragma unroll
  for (int pt = 0; pt < 4; ++pt)
#pragma unroll
    for (int ct = 0; ct < 4; ++ct) Y[pt][ct] = (f32x4){0.f, 0.f, 0.f, 0.f};
  float M[4], L[4];
#pragma unroll
  for (int pt = 0; pt < 4; ++pt) { M[pt] = -1e30f; L[pt] = 0.f; }

  u16* pb = pbuf + w * 4 * 16 * 32;
  const int swp = (l4 & 3) << 3;             // pbuf xor key

#pragma unroll
  for (int sc = 0; sc < 4; ++sc) {
    // coalesced operand loads (1KB each)
    s16x8 kf[2][2], vf[4];
#pragma unroll
    for (int h = 0; h < 2; ++h)
#pragma unroll
      for (int f = 0; f < 2; ++f)
        kf[h][f] = *(const s16x8*)(wb + BW_KF + ((((w * 8 + sc * 2 + h) * 2) + f) * 64 + lane) * 8);
#pragma unroll
    for (int ct = 0; ct < 4; ++ct)
      vf[ct] = *(const s16x8*)(wb + BW_VF + ((((w * 4 + sc) * 4) + ct) * 64 + lane) * 8);

    // QK^T: S[m 32][p 64] ; D row = m (g*4+r+16h), col = p (l4)
    f32x4 s_[2][4];
#pragma unroll
    for (int h = 0; h < 2; ++h)
#pragma unroll
      for (int pt = 0; pt < 4; ++pt) {
        f32x4 acc = {0.f, 0.f, 0.f, 0.f};
        acc = __builtin_amdgcn_mfma_f32_16x16x32_bf16(kf[h][0], q[pt][0], acc, 0, 0, 0);
        acc = __builtin_amdgcn_mfma_f32_16x16x32_bf16(kf[h][1], q[pt][1], acc, 0, 0, 0);
        s_[h][pt] = acc;
      }

    float facv[4];
#pragma unroll
    for (int pt = 0; pt < 4; ++pt) {
      float mx = s_[0][pt][0];
#pragma unroll
      for (int h = 0; h < 2; ++h)
#pragma unroll
        for (int r = 0; r < 4; ++r) mx = fmaxf(mx, s_[h][pt][r]);
      mx = fmaxf(mx, __shfl_xor(mx, 16, 64));
      mx = fmaxf(mx, __shfl_xor(mx, 32, 64));
      const float nM = fmaxf(M[pt], mx);
      facv[pt] = exp2f(M[pt] - nM);
      M[pt] = nM;
      float ls = 0.f;
#pragma unroll
      for (int h = 0; h < 2; ++h)
#pragma unroll
        for (int r = 0; r < 4; ++r) {
          const float e = exp2f(s_[h][pt][r] - nM);
          ls += e;
          pb[(pt * 16 + l4) * 32 + ((g * 4 + r + 16 * h) ^ swp)] = f2b(e);
        }
      ls += __shfl_xor(ls, 16, 64);
      ls += __shfl_xor(ls, 32, 64);
      L[pt] = L[pt] * facv[pt] + ls;
    }
#pragma unroll
    for (int pt = 0; pt < 4; ++pt)
#pragma unroll
      for (int ct = 0; ct < 4; ++ct) Y[pt][ct] *= facv[pt];

    asm volatile("s_waitcnt lgkmcnt(0)" ::: "memory");
    __builtin_amdgcn_sched_barrier(0);

    // PV: mfma(A=V^T, B=P) -> D[row=c][col=p]
#pragma unroll
    for (int pt = 0; pt < 4; ++pt) {
      const s16x8 pa = *(const s16x8*)&pb[(pt * 16 + l4) * 32 + ((g * 8) ^ swp)];
#pragma unroll
      for (int ct = 0; ct < 4; ++ct)
        Y[pt][ct] = __builtin_amdgcn_mfma_f32_16x16x32_bf16(vf[ct], pa, Y[pt][ct], 0, 0, 0);
    }
  }
  __syncthreads();   // all waves done with pbuf/pht before yp overlay

  // ---- publish partials ----
  if (g == 0) {
#pragma unroll
    for (int pt = 0; pt < 4; ++pt) {
      smax[(w * 4 + pt) * 16 + l4] = M[pt];
      ssum[(w * 4 + pt) * 16 + l4] = L[pt];
    }
  }
#pragma unroll
  for (int pt = 0; pt < 4; ++pt)
#pragma unroll
    for (int ct = 0; ct < 4; ++ct) {
      us4 pk;
#pragma unroll
      for (int r = 0; r < 4; ++r) pk[r] = f2b(Y[pt][ct][r]);
      *(us4*)&yp[((w * 64) + pt * 16 + l4) * 68 + ct * 16 + g * 4] = pk;
    }
  __syncthreads();

  // ---- merge: wave w combines c-block [w*16, +16) over the 4 m-quarters ----
#pragma unroll
  for (int pt = 0; pt < 4; ++pt) {
    const int p = pt * 16 + l4;
    float Ms[4], Lsrc[4];
#pragma unroll
    for (int w2 = 0; w2 < 4; ++w2) {
      Ms[w2]   = smax[(w2 * 4 + pt) * 16 + l4];
      Lsrc[w2] = ssum[(w2 * 4 + pt) * 16 + l4];
    }
    float Mstar = fmaxf(fmaxf(Ms[0], Ms[1]), fmaxf(Ms[2], Ms[3]));
    float acc4[4] = {0.f, 0.f, 0.f, 0.f};
    float Ls = 0.f;
#pragma unroll
    for (int w2 = 0; w2 < 4; ++w2) {
      const float fw = exp2f(Ms[w2] - Mstar);
      Ls += fw * Lsrc[w2];
      const us4 v = *(const us4*)&yp[((w2 * 64) + p) * 68 + w * 16 + g * 4];
#pragma unroll
      for (int r = 0; r < 4; ++r) acc4[r] += fw * b2f(v[r]);
    }
    const float inv = 1.f / Ls;
    us4 pk;
#pragma unroll
    for (int r = 0; r < 4; ++r) pk[r] = f2b(acc4[r] * inv);
    *(us4*)&yT[p * 64 + ((w * 16 + g * 4) ^ ((l4 & 7) << 3))] = pk;
  }
  __syncthreads();

  // ---- phase D: out = wz @ y + wz_b + x ----
  {
    const s16x8 a0 = *(const s16x8*)(wb + BW_WZF + (((w * 2 + 0) * 64) + lane) * 8);
    const s16x8 a1 = *(const s16x8*)(wb + BW_WZF + (((w * 2 + 1) * 64) + lane) * 8);
    float bz[4];
#pragma unroll
    for (int r = 0; r < 4; ++r) bz[r] = wz_b[w * 16 + g * 4 + r];
#pragma unroll
    for (int pt = 0; pt < 4; ++pt) {
      const int p = pt * 16 + l4;
      const int sw = (l4 & 7) << 3;
      const s16x8 b0 = *(const s16x8*)&yT[p * 64 + ((g * 8) ^ sw)];
      const s16x8 b1 = *(const s16x8*)&yT[p * 64 + ((32 + g * 8) ^ sw)];
      f32x4 acc = {0.f, 0.f, 0.f, 0.f};
      acc = __builtin_amdgcn_mfma_f32_16x16x32_bf16(a0, b0, acc, 0, 0, 0);
      acc = __builtin_amdgcn_mfma_f32_16x16x32_bf16(a1, b1, acc, 0, 0, 0);
#pragma unroll
      for (int r = 0; r < 4; ++r) {
        const size_t idx = ((size_t)b * 64 + w * 16 + g * 4 + r) * HW + p0 + pt * 16 + l4;
        out[idx] = acc[r] + bz[r] + x[idx];
      }
    }
  }
}

extern "C" void kernel_launch(void* const* d_in, const int* in_sizes, int n_in,
                              void* d_out, int out_size, void* d_ws, size_t ws_size,
                              hipStream_t stream) {
  const float* x     = (const float*)d_in[0];
  const float* gamma = (const float*)d_in[1];
  const float* beta  = (const float*)d_in[2];
  const float* phi_w = (const float*)d_in[3];
  const float* phi_b = (const float*)d_in[4];
  const float* mb    = (const float*)d_in[5];
  const float* wz_w  = (const float*)d_in[6];
  const float* wz_b  = (const float*)d_in[7];
  float* out = (float*)d_out;
  float* ws  = (float*)d_ws;

  k_stats<<<1024, 256, 0, stream>>>(x, ws);
  k_prep<<<32, 64, 0, stream>>>(phi_w, phi_b, gamma, beta, ws);
  k_tr<<<784, 256, 0, stream>>>(mb, wz_w, ws);
  k_main<<<NFRAME * 64, 256, 0, stream>>>(x, ws, wz_b, out);
}